// Round 6
// baseline (2558.649 us; speedup 1.0000x reference)
//
#include <hip/hip_runtime.h>
#include <cstdint>
#include <cstddef>

#define NN 16
#define DD 2048
#define BB 4096

#define TM 128
#define TN 128
#define BK 64
#define NBLK 512  // (BB/TM)*(DD/TN) = 32*16; 2 blocks/CU exact residency

typedef _Float16 half8 __attribute__((ext_vector_type(8)));
typedef _Float16 half4 __attribute__((ext_vector_type(4)));
typedef float f32x4 __attribute__((ext_vector_type(4)));

__device__ __forceinline__ float fast_tanh(float x) {
  float ax = __builtin_fabsf(x);
  float e = __expf(-2.0f * ax);
  float t = (1.0f - e) / (1.0f + e);
  return x < 0.0f ? -t : t;
}

// W fp32 [i][k][n] -> Wh fp16 [i][n][k].
// Register 4x4 transpose -> half4 b64 LDS writes, tile[64][68] (stride 136 B):
// write banks 8a+2j+8w+2c -> 4 lanes/bank-pair = wave64 b64 floor (conflict-
// free); reads 2x b64, banks 16w+2d+4e -> 4 lanes/pair (conflict-free).
// (r0 version had 16-way 2B ds_write_b16 conflicts; r3 version had scatter
// global stores. This one: coalesced global both sides + conflict-free LDS.)
__global__ __launch_bounds__(256) void wconv_kernel(const float* __restrict__ W,
                                                    _Float16* __restrict__ Wh) {
  __shared__ _Float16 tile[64][68];
  const int i = blockIdx.z;
  const int k0 = blockIdx.y * 64;
  const int n0 = blockIdx.x * 64;
  const float* Wi = W + (size_t)i * DD * DD;
  _Float16* Whi = Wh + (size_t)i * DD * DD;
  const int t = threadIdx.x;
  const int kb = (t >> 4) * 4;  // 4 consecutive k rows
  const int nb = (t & 15) * 4;  // 4 consecutive n cols (16 lanes = 256 B)
  float4 v[4];
#pragma unroll
  for (int r = 0; r < 4; ++r)
    v[r] = *(const float4*)(Wi + (size_t)(k0 + kb + r) * DD + n0 + nb);
#pragma unroll
  for (int j = 0; j < 4; ++j) {
    half4 o;
    o.x = (_Float16)((const float*)&v[0])[j];
    o.y = (_Float16)((const float*)&v[1])[j];
    o.z = (_Float16)((const float*)&v[2])[j];
    o.w = (_Float16)((const float*)&v[3])[j];
    *(half4*)&tile[nb + j][kb] = o;  // row n=nb+j gets k=kb..kb+3
  }
  __syncthreads();
  const int wr = t >> 3;
  const int wc = (t & 7) * 8;  // 8 lanes x 16 B = 128 B/row contiguous
#pragma unroll
  for (int p = 0; p < 2; ++p) {
    int n = p * 32 + wr;
    half4 lo = *(const half4*)&tile[n][wc];
    half4 hi = *(const half4*)&tile[n][wc + 4];
    half8 y;
    y[0] = lo.x; y[1] = lo.y; y[2] = lo.z; y[3] = lo.w;
    y[4] = hi.x; y[5] = hi.y; y[6] = hi.z; y[7] = hi.w;
    *(half8*)(Whi + (size_t)(n0 + n) * DD + k0 + wc) = y;
  }
}

// x fp32 -> S0 fp16 (elementwise, verified round-0 version)
__global__ __launch_bounds__(256) void xconv_kernel(const float* __restrict__ x,
                                                    _Float16* __restrict__ s0) {
  size_t idx = (size_t)(blockIdx.x * 256 + threadIdx.x) * 4;
  float4 v = *(const float4*)(x + idx);
  half4 o;
  o.x = (_Float16)v.x; o.y = (_Float16)v.y; o.z = (_Float16)v.z; o.w = (_Float16)v.w;
  *(half4*)(s0 + idx) = o;
}

// Zero the software-barrier state each graph replay.
__global__ void binit_kernel(unsigned* bar) {
  if (threadIdx.x < 32) bar[threadIdx.x] = 0u;
}

// Software grid barrier (graph-capture-safe; hipLaunchCooperativeKernel is
// not, as round 5 proved). Sense-reversing: arrivals fetch_add cnt; the
// 512th arriver resets cnt and release-increments gen; others acquire-spin
// on gen. Agent-scope acquire/release + __threadfence give cross-XCD L2
// wb/inv (Guideline 16). Deadlock-free iff all NBLK blocks resident:
// launch_bounds(256,2) caps VGPR<=128, LDS 64KB <= 160/2 -> 2/CU x 256 CU
// = 512 exact. Replay-safe: cnt ends at 0, gen only compared for change.
__device__ __forceinline__ void grid_sync(unsigned* cnt, unsigned* gen) {
  __syncthreads();  // all block's stores issued & vm-drained before arrival
  if (threadIdx.x == 0) {
    __threadfence();  // release our block's stores to device scope
    unsigned g = __hip_atomic_load(gen, __ATOMIC_RELAXED, __HIP_MEMORY_SCOPE_AGENT);
    unsigned a = __hip_atomic_fetch_add(cnt, 1u, __ATOMIC_ACQ_REL, __HIP_MEMORY_SCOPE_AGENT);
    if (a == NBLK - 1) {
      __hip_atomic_store(cnt, 0u, __ATOMIC_RELAXED, __HIP_MEMORY_SCOPE_AGENT);
      __hip_atomic_fetch_add(gen, 1u, __ATOMIC_RELEASE, __HIP_MEMORY_SCOPE_AGENT);
    } else {
      while (__hip_atomic_load(gen, __ATOMIC_ACQUIRE, __HIP_MEMORY_SCOPE_AGENT) == g)
        __builtin_amdgcn_s_sleep(8);
    }
    __threadfence();  // acquire side: invalidate stale cached lines
  }
  __syncthreads();
}

// Persistent kernel: all 16 DAG nodes in one dispatch. Per-node GEMM body is
// byte-identical to the verified round-0 node_gemm (128x128 tile, 4 waves x
// 64x64, BK=64, double-buffered LDS, one barrier/iter, XOR k-chunk swizzle,
// XCD-aware mapping, LDS-transposed epilogue). Between nodes: grid_sync.
__global__ __launch_bounds__(256, 2) void node_chain(
    const _Float16* __restrict__ Wh,    // [NN][DD][DD] fp16 [n][k]
    const float* __restrict__ bias_all, // [NN][DD]
    _Float16* __restrict__ S0,          // [BB][DD] ping
    _Float16* __restrict__ S1,          // [BB][DD] pong
    _Float16* __restrict__ Y0,          // [BB][DD] ping
    _Float16* __restrict__ Y1,          // [BB][DD] pong
    float* __restrict__ Ofinal,         // [BB][DD] terminal fp32 output
    unsigned* __restrict__ bar)         // barrier state {cnt, gen}
{
  __shared__ _Float16 smem[4 * TM * BK];  // 64 KB

  unsigned* cnt = bar;
  unsigned* gen = bar + 16;  // separate 64-B line

  const int t = threadIdx.x;
  const int lane = t & 63;
  const int wave = t >> 6;
  const int bid = blockIdx.x;
  const int n0 = (bid & 15) * TN;  // XCD (bid%8) owns n-tiles {x, x+8}
  const int m0 = (bid >> 4) * TM;
  const int wm = (wave & 1) * 64;  // wave tile: 64m x 64n
  const int wn = (wave >> 1) * 64;
  const int lrow = lane & 15;
  const int lq = lane >> 4;

  // Staging geometry (node-invariant): thread t covers rows srow+32r
  // (r=0..3), chunk c = t&7 (16B). XOR swizzle: LDS[row][c*8..] holds global
  // k-chunk (c ^ (row&7)); row&7 invariant under +32-row steps.
  const int srow = t >> 3;
  const int ska = ((t & 7) ^ (srow & 7)) * 8;

  for (int node = 0; node < NN; ++node) {
    const _Float16* S = (node & 1) ? S1 : S0;
    _Float16* Snext = (node & 1) ? S0 : S1;
    _Float16* Y = (node & 1) ? Y1 : Y0;
    const _Float16* Yprev = (node >= 1) ? ((node & 1) ? Y0 : Y1) : nullptr;
    const _Float16* Wt = Wh + (size_t)node * DD * DD;
    const float* bias = bias_all + (size_t)node * DD;
    const bool last = (node == NN - 1);

    f32x4 acc[4][4];
#pragma unroll
    for (int i = 0; i < 4; ++i)
#pragma unroll
      for (int j = 0; j < 4; ++j) acc[i][j] = (f32x4)0.0f;

    const _Float16* ag = S + (size_t)(m0 + srow) * DD + ska;
    const _Float16* bg = Wt + (size_t)(n0 + srow) * DD + ska;

    auto stage = [&](int p, int k0) {
      const _Float16* a = ag + k0;
      const _Float16* b = bg + k0;
      _Float16* al = smem + p * (TM * BK) + t * 8;
      _Float16* bl = smem + 2 * (TM * BK) + p * (TN * BK) + t * 8;
#pragma unroll
      for (int r = 0; r < 4; ++r) {
        __builtin_amdgcn_global_load_lds(
            (const __attribute__((address_space(1))) void*)(a + (size_t)(r * 32) * DD),
            (__attribute__((address_space(3))) void*)(al + r * 2048), 16, 0, 0);
        __builtin_amdgcn_global_load_lds(
            (const __attribute__((address_space(1))) void*)(b + (size_t)(r * 32) * DD),
            (__attribute__((address_space(3))) void*)(bl + r * 2048), 16, 0, 0);
      }
    };

    stage(0, 0);

    for (int i = 0; i < DD / BK; ++i) {
      __syncthreads();  // publishes buf i&1
      if (i < DD / BK - 1) stage((i + 1) & 1, (i + 1) * BK);
      const _Float16* Ap = smem + (i & 1) * (TM * BK);
      const _Float16* Bp = smem + 2 * (TM * BK) + (i & 1) * (TN * BK);
#pragma unroll
      for (int ks = 0; ks < BK; ks += 32) {
        const int cx = (((ks >> 3) + lq) ^ (lrow & 7)) * 8;
        half8 a[4], b[4];
#pragma unroll
        for (int mt = 0; mt < 4; ++mt)
          a[mt] = *(const half8*)(Ap + (wm + mt * 16 + lrow) * BK + cx);
#pragma unroll
        for (int nt = 0; nt < 4; ++nt)
          b[nt] = *(const half8*)(Bp + (wn + nt * 16 + lrow) * BK + cx);
#pragma unroll
        for (int mt = 0; mt < 4; ++mt)
#pragma unroll
          for (int nt = 0; nt < 4; ++nt)
            acc[mt][nt] =
                __builtin_amdgcn_mfma_f32_16x16x32_f16(a[mt], b[nt], acc[mt][nt], 0, 0, 0);
      }
    }

    // Epilogue: acc -> LDS (fp16, [128][128]) -> coalesced global stores.
    __syncthreads();
    _Float16* CT = smem;  // 32 KB, reuse A region
    float bv[4];
#pragma unroll
    for (int nt = 0; nt < 4; ++nt) bv[nt] = bias[n0 + wn + nt * 16 + lrow];
#pragma unroll
    for (int mt = 0; mt < 4; ++mt)
#pragma unroll
      for (int nt = 0; nt < 4; ++nt)
#pragma unroll
        for (int r = 0; r < 4; ++r) {
          int row = wm + mt * 16 + lq * 4 + r;
          int col = wn + nt * 16 + lrow;
          CT[row * TN + col] = (_Float16)fast_tanh(acc[mt][nt][r] + bv[nt]);
        }
    __syncthreads();

#pragma unroll
    for (int pp = 0; pp < 8; ++pp) {
      int idx = pp * 2048 + t * 8;
      int row = idx >> 7;
      int col = idx & 127;
      size_t off = (size_t)(m0 + row) * DD + n0 + col;
      half8 y = *(const half8*)&CT[idx];
      if (last) {
        float4 f0 = {(float)y[0], (float)y[1], (float)y[2], (float)y[3]};
        float4 f1 = {(float)y[4], (float)y[5], (float)y[6], (float)y[7]};
        *(float4*)(Ofinal + off) = f0;
        *(float4*)(Ofinal + off + 4) = f1;
      } else {
        *(half8*)(Y + off) = y;
        half8 s = y;
        if (Yprev) s = s + *(const half8*)(Yprev + off);
        *(half8*)(Snext + off) = s;
      }
    }

    if (!last) grid_sync(cnt, gen);
  }
}

extern "C" void kernel_launch(void* const* d_in, const int* in_sizes, int n_in,
                              void* d_out, int out_size, void* d_ws, size_t ws_size,
                              hipStream_t stream) {
  const float* x = (const float*)d_in[0];
  const float* W = (const float*)d_in[1];
  const float* b = (const float*)d_in[2];
  float* out = (float*)d_out;
  char* ws = (char*)d_ws;

  _Float16* Wh = (_Float16*)ws;  // 128 MB
  size_t wbytes = (size_t)NN * DD * DD * sizeof(_Float16);
  size_t sbytes = (size_t)BB * DD * sizeof(_Float16);  // 16 MB each
  _Float16* S0 = (_Float16*)(ws + wbytes);
  _Float16* S1 = S0 + (size_t)BB * DD;
  _Float16* Y0 = S1 + (size_t)BB * DD;
  _Float16* Y1 = Y0 + (size_t)BB * DD;
  unsigned* bar = (unsigned*)(ws + wbytes + 4 * sbytes);

  binit_kernel<<<dim3(1), dim3(64), 0, stream>>>(bar);
  wconv_kernel<<<dim3(DD / 64, DD / 64, NN), dim3(256), 0, stream>>>(W, Wh);
  xconv_kernel<<<dim3((BB * DD) / 1024), dim3(256), 0, stream>>>(x, S0);

  node_chain<<<dim3(NBLK), dim3(256), 0, stream>>>(Wh, b, S0, S1, Y0, Y1, out, bar);
  (void)in_sizes; (void)n_in; (void)out_size; (void)ws_size;
}